// Round 1
// baseline (1149.676 us; speedup 1.0000x reference)
//
#include <hip/hip_runtime.h>
#include <hip/hip_bf16.h>
#include <cstdint>

#define NU 50000
#define NI 50000
#define EE 800000
#define DIN 256
#define NH 4
#define DOUT 32
#define HD 128      // NH*DOUT
#define WCOLS 168   // [hs 128 | loop 32 | wl 4 | wr 4]

__device__ __forceinline__ float leakyf(float x){ return x > 0.f ? x : 0.2f*x; }
__device__ __forceinline__ float eluf(float x){ return x > 0.f ? x : expm1f(x); }

// monotone float->uint mapping for atomicMax on floats
__device__ __forceinline__ unsigned fmap(float x){
  unsigned b = __float_as_uint(x);
  return (b & 0x80000000u) ? ~b : (b | 0x80000000u);
}
__device__ __forceinline__ float funmap_guard(unsigned u){
  unsigned b = (u & 0x80000000u) ? (u ^ 0x80000000u) : ~u;
  float f = __uint_as_float(b);
  return isfinite(f) ? f : 0.f;   // u==0 (no edges) -> NaN -> 0 (zero-in-degree guard)
}

// Build W[256 x 168] = [fc_a(128) | loop(32) | wl(4)=fc_a.attn_l_a | wr(4)=fc_b.attn_r_b]
__global__ void pack_w(const float* __restrict__ fc_a, const float* __restrict__ attn_l_a,
                       const float* __restrict__ fc_b, const float* __restrict__ attn_r_b,
                       const float* __restrict__ loopw, float* __restrict__ W) {
  int t = blockIdx.x*blockDim.x + threadIdx.x;
  if (t >= DIN*WCOLS) return;
  int k = t / WCOLS, j = t - k*WCOLS;
  float v;
  if (j < HD) v = fc_a[k*HD + j];
  else if (j < HD+DOUT) v = loopw[k*DOUT + (j-HD)];
  else if (j < HD+DOUT+NH) {
    int h = j - (HD+DOUT); float s = 0.f;
    for (int d = 0; d < DOUT; ++d) s += fc_a[k*HD + h*DOUT + d] * attn_l_a[h*DOUT + d];
    v = s;
  } else {
    int h = j - (HD+DOUT+NH); float s = 0.f;
    for (int d = 0; d < DOUT; ++d) s += fc_b[k*HD + h*DOUT + d] * attn_r_b[h*DOUT + d];
    v = s;
  }
  W[t] = v;
}

// C[M,N] = A[M,256] @ B[256,N]; 64x64 tile, 256 threads, 4x4 per thread
__global__ __launch_bounds__(256) void gemm_f32(const float* __restrict__ A,
                                                const float* __restrict__ B,
                                                float* __restrict__ C, int M, int N) {
  __shared__ float As[16][68];   // [k][row], padded for float4-aligned reads
  __shared__ float Bs[16][68];   // [k][col]
  int t = threadIdx.x;
  int bm = blockIdx.x * 64, bn = blockIdx.y * 64;
  int tx = t & 15, ty = t >> 4;
  float acc[4][4] = {};
  int arow = t >> 2, akk = (t & 3) * 4;
  int bcol = t & 63, bkk = t >> 6;
  for (int k0 = 0; k0 < DIN; k0 += 16) {
    float4 av = make_float4(0.f,0.f,0.f,0.f);
    if (bm + arow < M)
      av = *reinterpret_cast<const float4*>(A + (bm+arow)*DIN + k0 + akk);
    As[akk+0][arow] = av.x; As[akk+1][arow] = av.y;
    As[akk+2][arow] = av.z; As[akk+3][arow] = av.w;
    int gc = bn + bcol;
    #pragma unroll
    for (int i = 0; i < 4; ++i) {
      int kk = bkk + i*4;
      Bs[kk][bcol] = (gc < N) ? B[(k0+kk)*N + gc] : 0.f;
    }
    __syncthreads();
    #pragma unroll
    for (int kk = 0; kk < 16; ++kk) {
      float4 a = *reinterpret_cast<const float4*>(&As[kk][ty*4]);
      float4 b = *reinterpret_cast<const float4*>(&Bs[kk][tx*4]);
      acc[0][0] += a.x*b.x; acc[0][1] += a.x*b.y; acc[0][2] += a.x*b.z; acc[0][3] += a.x*b.w;
      acc[1][0] += a.y*b.x; acc[1][1] += a.y*b.y; acc[1][2] += a.y*b.z; acc[1][3] += a.y*b.w;
      acc[2][0] += a.z*b.x; acc[2][1] += a.z*b.y; acc[2][2] += a.z*b.z; acc[2][3] += a.z*b.w;
      acc[3][0] += a.w*b.x; acc[3][1] += a.w*b.y; acc[3][2] += a.w*b.z; acc[3][3] += a.w*b.w;
    }
    __syncthreads();
  }
  #pragma unroll
  for (int r = 0; r < 4; ++r) {
    int gr = bm + ty*4 + r;
    if (gr >= M) continue;
    #pragma unroll
    for (int c = 0; c < 4; ++c) {
      int gc = bn + tx*4 + c;
      if (gc < N) C[gr*N + gc] = acc[r][c];
    }
  }
}

// pass 1: segment max of leaky(el[src]+er[dst]) over dst
__global__ void edge_max(const int* __restrict__ src, const int* __restrict__ dst,
                         const float* __restrict__ srcbuf, const float* __restrict__ dstbuf,
                         unsigned* __restrict__ emax) {
  int t = blockIdx.x*blockDim.x + threadIdx.x;
  if (t >= EE*NH) return;
  int e = t >> 2, h = t & 3;
  int s = src[e], d = dst[e];
  float sc = leakyf(srcbuf[s*WCOLS + HD+DOUT + h] + dstbuf[d*WCOLS + HD+DOUT+NH + h]);
  atomicMax(&emax[d*NH + h], fmap(sc));
}

// pass 2: ex = exp(score - emax[dst]); agg[dst] += ex * hs[src]; denom[dst] += ex
__global__ void edge_msg(const int* __restrict__ src, const int* __restrict__ dst,
                         const float* __restrict__ srcbuf, const float* __restrict__ dstbuf,
                         const unsigned* __restrict__ emax,
                         float* __restrict__ denom, float* __restrict__ agg) {
  int t = blockIdx.x*blockDim.x + threadIdx.x;
  int e = t >> 7;
  if (e >= EE) return;
  int j = t & 127, h = j >> 5;
  int s = src[e], d = dst[e];
  float sc = leakyf(srcbuf[s*WCOLS + HD+DOUT + h] + dstbuf[d*WCOLS + HD+DOUT+NH + h]);
  float mx = funmap_guard(emax[d*NH + h]);
  float ex = expf(sc - mx);
  atomicAdd(&agg[d*HD + j], ex * srcbuf[s*WCOLS + j]);
  if ((j & 31) == 0) atomicAdd(&denom[d*NH + h], ex);
}

// pass 3: out = elu(elu(agg/max(denom,1e-9)) + loop)   (in place on d_out half)
__global__ void finalize_k(float* __restrict__ out, const float* __restrict__ denom,
                           const float* __restrict__ dstbuf, int N) {
  int t = blockIdx.x*blockDim.x + threadIdx.x;
  if (t >= N*HD) return;
  int i = t >> 7, j = t & 127, h = j >> 5;
  float v = out[t] / fmaxf(denom[i*NH + h], 1e-9f);
  v = eluf(v);
  v = eluf(v + dstbuf[i*WCOLS + HD + (j & 31)]);
  out[t] = v;
}

extern "C" void kernel_launch(void* const* d_in, const int* in_sizes, int n_in,
                              void* d_out, int out_size, void* d_ws, size_t ws_size,
                              hipStream_t stream) {
  const float* feat_user  = (const float*)d_in[0];
  const float* feat_item  = (const float*)d_in[1];
  const int*   src_r1     = (const int*)d_in[2];
  const int*   dst_r1     = (const int*)d_in[3];
  const int*   src_r2     = (const int*)d_in[4];
  const int*   dst_r2     = (const int*)d_in[5];
  const float* fc_r1      = (const float*)d_in[6];
  const float* attn_l_r1  = (const float*)d_in[7];
  const float* attn_r_r1  = (const float*)d_in[8];
  const float* fc_r2      = (const float*)d_in[9];
  const float* attn_l_r2  = (const float*)d_in[10];
  const float* attn_r_r2  = (const float*)d_in[11];
  const float* loopw      = (const float*)d_in[12];

  float* out    = (float*)d_out;
  float* h_user = out;            // (50000,4,32) from relation 2
  float* h_item = out + NU*HD;    // (50000,4,32) from relation 1

  float*    ws       = (float*)d_ws;
  float*    out_user = ws;                          // 50000*168
  float*    out_item = out_user + NU*WCOLS;         // 50000*168
  float*    W_user   = out_item + NI*WCOLS;         // 256*168
  float*    W_item   = W_user + DIN*WCOLS;          // 256*168
  unsigned* emax1    = (unsigned*)(W_item + DIN*WCOLS);  // 50000*4
  float*    denom1   = (float*)(emax1 + NI*NH);          // 50000*4
  unsigned* emax2    = (unsigned*)(denom1 + NI*NH);      // 50000*4
  float*    denom2   = (float*)(emax2 + NU*NH);          // 50000*4

  // zero accumulators (emax init 0 is below all mapped real scores)
  hipMemsetAsync(d_out, 0, sizeof(float)*2*NU*HD, stream);
  hipMemsetAsync(emax1, 0, sizeof(unsigned)*4*NU*NH, stream);

  // W_user: hs via fc_r1 (src of r1), el_r1 (attn_l_r1.fc_r1), er_r2 (attn_r_r2.fc_r2)
  pack_w<<<(DIN*WCOLS+255)/256, 256, 0, stream>>>(fc_r1, attn_l_r1, fc_r2, attn_r_r2, loopw, W_user);
  // W_item: hs via fc_r2 (src of r2), el_r2 (attn_l_r2.fc_r2), er_r1 (attn_r_r1.fc_r1)
  pack_w<<<(DIN*WCOLS+255)/256, 256, 0, stream>>>(fc_r2, attn_l_r2, fc_r1, attn_r_r1, loopw, W_item);

  dim3 gg((NU + 63)/64, (WCOLS + 63)/64);
  gemm_f32<<<gg, 256, 0, stream>>>(feat_user, W_user, out_user, NU, WCOLS);
  gemm_f32<<<gg, 256, 0, stream>>>(feat_item, W_item, out_item, NI, WCOLS);

  // relation 1: user -> item  (dst = item -> h_item)
  edge_max<<<(EE*NH+255)/256, 256, 0, stream>>>(src_r1, dst_r1, out_user, out_item, emax1);
  edge_msg<<<(EE*HD)/256, 256, 0, stream>>>(src_r1, dst_r1, out_user, out_item, emax1, denom1, h_item);
  finalize_k<<<(NI*HD)/256, 256, 0, stream>>>(h_item, denom1, out_item, NI);

  // relation 2: item -> user  (dst = user -> h_user)
  edge_max<<<(EE*NH+255)/256, 256, 0, stream>>>(src_r2, dst_r2, out_item, out_user, emax2);
  edge_msg<<<(EE*HD)/256, 256, 0, stream>>>(src_r2, dst_r2, out_item, out_user, emax2, denom2, h_user);
  finalize_k<<<(NU*HD)/256, 256, 0, stream>>>(h_user, denom2, out_user, NU);
}

// Round 2
// 761.224 us; speedup vs baseline: 1.5103x; 1.5103x over previous
//
#include <hip/hip_runtime.h>
#include <hip/hip_bf16.h>
#include <cstdint>

#define NU 50000
#define NI 50000
#define NN 50000     // both node sets are 50000
#define EE 800000
#define DIN 256
#define NH 4
#define DOUT 32
#define HD 128      // NH*DOUT
#define WCOLS 168   // [hs 128 | loop 32 | wl 4 | wr 4]

__device__ __forceinline__ float leakyf(float x){ return x > 0.f ? x : 0.2f*x; }
__device__ __forceinline__ float eluf(float x){ return x > 0.f ? x : expm1f(x); }

// Build W[256 x 168] = [fc_a(128) | loop(32) | wl(4)=fc_a.attn_l_a | wr(4)=fc_b.attn_r_b]
__global__ void pack_w(const float* __restrict__ fc_a, const float* __restrict__ attn_l_a,
                       const float* __restrict__ fc_b, const float* __restrict__ attn_r_b,
                       const float* __restrict__ loopw, float* __restrict__ W) {
  int t = blockIdx.x*blockDim.x + threadIdx.x;
  if (t >= DIN*WCOLS) return;
  int k = t / WCOLS, j = t - k*WCOLS;
  float v;
  if (j < HD) v = fc_a[k*HD + j];
  else if (j < HD+DOUT) v = loopw[k*DOUT + (j-HD)];
  else if (j < HD+DOUT+NH) {
    int h = j - (HD+DOUT); float s = 0.f;
    for (int d = 0; d < DOUT; ++d) s += fc_a[k*HD + h*DOUT + d] * attn_l_a[h*DOUT + d];
    v = s;
  } else {
    int h = j - (HD+DOUT+NH); float s = 0.f;
    for (int d = 0; d < DOUT; ++d) s += fc_b[k*HD + h*DOUT + d] * attn_r_b[h*DOUT + d];
    v = s;
  }
  W[t] = v;
}

// C[M,N] = A[M,256] @ B[256,N]; 64x64 tile, 256 threads, 4x4 per thread
__global__ __launch_bounds__(256) void gemm_f32(const float* __restrict__ A,
                                                const float* __restrict__ B,
                                                float* __restrict__ C, int M, int N) {
  __shared__ float As[16][68];
  __shared__ float Bs[16][68];
  int t = threadIdx.x;
  int bm = blockIdx.x * 64, bn = blockIdx.y * 64;
  int tx = t & 15, ty = t >> 4;
  float acc[4][4] = {};
  int arow = t >> 2, akk = (t & 3) * 4;
  int bcol = t & 63, bkk = t >> 6;
  for (int k0 = 0; k0 < DIN; k0 += 16) {
    float4 av = make_float4(0.f,0.f,0.f,0.f);
    if (bm + arow < M)
      av = *reinterpret_cast<const float4*>(A + (bm+arow)*DIN + k0 + akk);
    As[akk+0][arow] = av.x; As[akk+1][arow] = av.y;
    As[akk+2][arow] = av.z; As[akk+3][arow] = av.w;
    int gc = bn + bcol;
    #pragma unroll
    for (int i = 0; i < 4; ++i) {
      int kk = bkk + i*4;
      Bs[kk][bcol] = (gc < N) ? B[(k0+kk)*N + gc] : 0.f;
    }
    __syncthreads();
    #pragma unroll
    for (int kk = 0; kk < 16; ++kk) {
      float4 a = *reinterpret_cast<const float4*>(&As[kk][ty*4]);
      float4 b = *reinterpret_cast<const float4*>(&Bs[kk][tx*4]);
      acc[0][0] += a.x*b.x; acc[0][1] += a.x*b.y; acc[0][2] += a.x*b.z; acc[0][3] += a.x*b.w;
      acc[1][0] += a.y*b.x; acc[1][1] += a.y*b.y; acc[1][2] += a.y*b.z; acc[1][3] += a.y*b.w;
      acc[2][0] += a.z*b.x; acc[2][1] += a.z*b.y; acc[2][2] += a.z*b.z; acc[2][3] += a.z*b.w;
      acc[3][0] += a.w*b.x; acc[3][1] += a.w*b.y; acc[3][2] += a.w*b.z; acc[3][3] += a.w*b.w;
    }
    __syncthreads();
  }
  #pragma unroll
  for (int r = 0; r < 4; ++r) {
    int gr = bm + ty*4 + r;
    if (gr >= M) continue;
    #pragma unroll
    for (int c = 0; c < 4; ++c) {
      int gc = bn + tx*4 + c;
      if (gc < N) C[gr*N + gc] = acc[r][c];
    }
  }
}

// histogram of dst degrees: deg[0..NN) for rel1, deg[NN..2NN) for rel2
__global__ void hist_k(const int* __restrict__ d1, const int* __restrict__ d2,
                       int* __restrict__ deg) {
  int t = blockIdx.x*blockDim.x + threadIdx.x;
  if (t < EE) atomicAdd(&deg[d1[t]], 1);
  else if (t < 2*EE) atomicAdd(&deg[NN + d2[t-EE]], 1);
}

// exclusive scan of deg -> offs (n+1) and cursor (n). One block per relation.
__global__ __launch_bounds__(1024) void scan_k(const int* __restrict__ deg,
                                               int* __restrict__ offs,
                                               int* __restrict__ cursor, int n) {
  int rel = blockIdx.x;
  const int* dg = deg + rel * n;
  int* of = offs + rel * (n + 1);
  int* cu = cursor + rel * n;
  __shared__ int wsum[16];
  __shared__ int chunk_tot;
  __shared__ int carry_s;
  int lane = threadIdx.x & 63, wid = threadIdx.x >> 6;
  if (threadIdx.x == 0) carry_s = 0;
  __syncthreads();
  for (int base = 0; base < n; base += 1024) {
    int i = base + threadIdx.x;
    int v = (i < n) ? dg[i] : 0;
    int x = v;
    #pragma unroll
    for (int st = 1; st < 64; st <<= 1) {
      int y = __shfl_up(x, st);
      if (lane >= st) x += y;
    }
    if (lane == 63) wsum[wid] = x;
    __syncthreads();
    if (threadIdx.x == 0) {
      int run = 0;
      #pragma unroll
      for (int w = 0; w < 16; ++w) { int tv = wsum[w]; wsum[w] = run; run += tv; }
      chunk_tot = run;
    }
    __syncthreads();
    int exc = x - v + wsum[wid] + carry_s;
    if (i < n) { of[i] = exc; cu[i] = exc; }
    __syncthreads();
    if (threadIdx.x == 0) carry_s += chunk_tot;
    __syncthreads();
  }
  if (threadIdx.x == 0) of[n] = carry_s;
}

// scatter src ids into CSR order
__global__ void scatter_k(const int* __restrict__ s1, const int* __restrict__ d1,
                          const int* __restrict__ s2, const int* __restrict__ d2,
                          int* __restrict__ cursor,
                          int* __restrict__ sorted1, int* __restrict__ sorted2) {
  int t = blockIdx.x*blockDim.x + threadIdx.x;
  if (t < EE) {
    int pos = atomicAdd(&cursor[d1[t]], 1);
    sorted1[pos] = s1[t];
  } else if (t < 2*EE) {
    int e = t - EE;
    int pos = atomicAdd(&cursor[NN + d2[e]], 1);
    sorted2[pos] = s2[e];
  }
}

// one wave per dst node: segment max + exp-weighted gather-sum + fused finalize.
// lane l covers output cols l and l+64; heads h_a=l>>5 (0/1), h_b=2+h_a.
__global__ __launch_bounds__(256) void agg_k(const float* __restrict__ srcbuf,
                                             const float* __restrict__ dstbuf,
                                             const int* __restrict__ offs,
                                             const int* __restrict__ ssrc,
                                             float* __restrict__ out, int N) {
  int gw = (blockIdx.x*blockDim.x + threadIdx.x) >> 6;
  int l = threadIdx.x & 63;
  if (gw >= N) return;
  int d = gw;
  int h_a = l >> 5, h_b = 2 + h_a;
  int beg = offs[d], end = offs[d+1];
  const float* drow = dstbuf + (size_t)d * WCOLS;
  float er_a = drow[HD+DOUT+NH + h_a], er_b = drow[HD+DOUT+NH + h_b];
  // pass 1: segment max (each half-wave computes its heads' scores redundantly)
  float mx_a = -1e30f, mx_b = -1e30f;
  for (int p = beg; p < end; ++p) {
    int s = ssrc[p];
    const float* sr = srcbuf + (size_t)s * WCOLS;
    mx_a = fmaxf(mx_a, leakyf(sr[HD+DOUT + h_a] + er_a));
    mx_b = fmaxf(mx_b, leakyf(sr[HD+DOUT + h_b] + er_b));
  }
  // pass 2: weighted sum
  float acc0 = 0.f, acc1 = 0.f, dn_a = 0.f, dn_b = 0.f;
  for (int p = beg; p < end; ++p) {
    int s = ssrc[p];
    const float* sr = srcbuf + (size_t)s * WCOLS;
    float ex_a = __expf(leakyf(sr[HD+DOUT + h_a] + er_a) - mx_a);
    float ex_b = __expf(leakyf(sr[HD+DOUT + h_b] + er_b) - mx_b);
    dn_a += ex_a; dn_b += ex_b;              // identical across half-wave lanes
    acc0 += ex_a * sr[l];
    acc1 += ex_b * sr[64 + l];
  }
  float v0 = eluf(acc0 / fmaxf(dn_a, 1e-9f));
  float v1 = eluf(acc1 / fmaxf(dn_b, 1e-9f));
  float lp = drow[HD + (l & 31)];            // loop col: (l%32) == ((l+64)%32)
  v0 = eluf(v0 + lp);
  v1 = eluf(v1 + lp);
  out[(size_t)d*HD + l]      = v0;
  out[(size_t)d*HD + 64 + l] = v1;
}

extern "C" void kernel_launch(void* const* d_in, const int* in_sizes, int n_in,
                              void* d_out, int out_size, void* d_ws, size_t ws_size,
                              hipStream_t stream) {
  const float* feat_user  = (const float*)d_in[0];
  const float* feat_item  = (const float*)d_in[1];
  const int*   src_r1     = (const int*)d_in[2];
  const int*   dst_r1     = (const int*)d_in[3];
  const int*   src_r2     = (const int*)d_in[4];
  const int*   dst_r2     = (const int*)d_in[5];
  const float* fc_r1      = (const float*)d_in[6];
  const float* attn_l_r1  = (const float*)d_in[7];
  const float* attn_r_r1  = (const float*)d_in[8];
  const float* fc_r2      = (const float*)d_in[9];
  const float* attn_l_r2  = (const float*)d_in[10];
  const float* attn_r_r2  = (const float*)d_in[11];
  const float* loopw      = (const float*)d_in[12];

  float* out    = (float*)d_out;
  float* h_user = out;            // (50000,4,32) from relation 2
  float* h_item = out + NU*HD;    // (50000,4,32) from relation 1

  float* ws       = (float*)d_ws;
  float* out_user = ws;                          // 50000*168
  float* out_item = out_user + NU*WCOLS;         // 50000*168
  float* W_user   = out_item + NI*WCOLS;         // 256*168
  float* W_item   = W_user + DIN*WCOLS;          // 256*168
  int*   deg      = (int*)(W_item + DIN*WCOLS);  // 2*50000
  int*   offs     = deg + 2*NN;                  // 2*(50000+1)
  int*   cursor   = offs + 2*(NN+1);             // 2*50000
  int*   sorted1  = cursor + 2*NN;               // 800000
  int*   sorted2  = sorted1 + EE;                // 800000

  hipMemsetAsync(deg, 0, sizeof(int)*2*NN, stream);

  // W_user: hs via fc_r1 (src of r1), el_r1, er_r2 (user is dst of r2)
  pack_w<<<(DIN*WCOLS+255)/256, 256, 0, stream>>>(fc_r1, attn_l_r1, fc_r2, attn_r_r2, loopw, W_user);
  // W_item: hs via fc_r2 (src of r2), el_r2, er_r1 (item is dst of r1)
  pack_w<<<(DIN*WCOLS+255)/256, 256, 0, stream>>>(fc_r2, attn_l_r2, fc_r1, attn_r_r1, loopw, W_item);

  dim3 gg((NU + 63)/64, (WCOLS + 63)/64);
  gemm_f32<<<gg, 256, 0, stream>>>(feat_user, W_user, out_user, NU, WCOLS);
  gemm_f32<<<gg, 256, 0, stream>>>(feat_item, W_item, out_item, NI, WCOLS);

  // CSR build (both relations)
  hist_k<<<(2*EE + 255)/256, 256, 0, stream>>>(dst_r1, dst_r2, deg);
  scan_k<<<2, 1024, 0, stream>>>(deg, offs, cursor, NN);
  scatter_k<<<(2*EE + 255)/256, 256, 0, stream>>>(src_r1, dst_r1, src_r2, dst_r2,
                                                  cursor, sorted1, sorted2);

  // relation 1: user -> item  (dst = item -> h_item)
  agg_k<<<(NI*64 + 255)/256, 256, 0, stream>>>(out_user, out_item, offs, sorted1, h_item, NI);
  // relation 2: item -> user  (dst = user -> h_user)
  agg_k<<<(NU*64 + 255)/256, 256, 0, stream>>>(out_item, out_user, offs + (NN+1), sorted2, h_user, NU);
}

// Round 3
// 596.660 us; speedup vs baseline: 1.9269x; 1.2758x over previous
//
#include <hip/hip_runtime.h>
#include <hip/hip_bf16.h>
#include <cstdint>

#define NU 50000
#define NI 50000
#define NN 50000
#define EE 800000
#define DIN 256
#define NH 4
#define DOUT 32
#define HD 128       // NH*DOUT
#define WC 176       // padded GEMM cols: [hs 128 | loop 32 | el 4 | er 4 | pad 8]
#define NCH 196      // ceil(NN/256)

typedef __attribute__((ext_vector_type(8))) short short8;
typedef __attribute__((ext_vector_type(4))) float f32x4;

__device__ __forceinline__ float leakyf(float x){ return x > 0.f ? x : 0.2f*x; }
__device__ __forceinline__ float eluf(float x){ return x > 0.f ? x : expm1f(x); }
__device__ __forceinline__ unsigned short f2bf(float x){
  unsigned u = __float_as_uint(x);
  return (unsigned short)((u + 0x7FFFu + ((u >> 16) & 1u)) >> 16);   // RNE
}
__device__ __forceinline__ float bf2f(unsigned short b){
  return __uint_as_float(((unsigned)b) << 16);
}

// Wt[c][k] bf16, c<176 (cols 168-175 zero), k<256.
// cols: [0,128) fc_a; [128,160) loop; [160,164) fc_a.attn_l_a; [164,168) fc_b.attn_r_b
__global__ void pack_wt(const float* __restrict__ fc_a, const float* __restrict__ attn_l_a,
                        const float* __restrict__ fc_b, const float* __restrict__ attn_r_b,
                        const float* __restrict__ loopw, unsigned short* __restrict__ Wt) {
  int t = blockIdx.x*blockDim.x + threadIdx.x;
  if (t >= WC*DIN) return;
  int c = t >> 8, k = t & 255;
  float v = 0.f;
  if (c < HD) v = fc_a[k*HD + c];
  else if (c < HD+DOUT) v = loopw[k*DOUT + (c-HD)];
  else if (c < HD+DOUT+NH) {
    int h = c - (HD+DOUT); float s = 0.f;
    for (int dd = 0; dd < DOUT; ++dd) s += fc_a[k*HD + h*DOUT + dd] * attn_l_a[h*DOUT + dd];
    v = s;
  } else if (c < HD+DOUT+2*NH) {
    int h = c - (HD+DOUT+NH); float s = 0.f;
    for (int dd = 0; dd < DOUT; ++dd) s += fc_b[k*HD + h*DOUT + dd] * attn_r_b[h*DOUT + dd];
    v = s;
  }
  Wt[t] = f2bf(v);
}

// MFMA GEMM: A[M][256] f32 -> (A @ W)[M][176], split-written to hsb/loopb/scb.
// Block: 256 thr = 4 waves, tile 64 rows. Wave w: rows w*16..w*16+15, all 11 col-frags.
__global__ __launch_bounds__(256) void gemm_mfma(const float* __restrict__ A,
                                                 const unsigned short* __restrict__ Wt,
                                                 unsigned short* __restrict__ hsb,
                                                 unsigned short* __restrict__ loopb,
                                                 float* __restrict__ scb, int M) {
  __shared__ __align__(16) unsigned short As[64*40];   // rows padded 32->40
  __shared__ __align__(16) unsigned short Ws[176*40];
  int t = threadIdx.x;
  int bm = blockIdx.x * 64;
  int w = t >> 6, l = t & 63;
  int r16 = l & 15, g4 = l >> 4;
  f32x4 acc[11];
  #pragma unroll
  for (int f = 0; f < 11; ++f) acc[f] = (f32x4){0.f,0.f,0.f,0.f};

  for (int k0 = 0; k0 < DIN; k0 += 32) {
    { // stage A tile 64x32, f32 -> bf16
      int row = t >> 2, off = (t & 3) * 8;
      int gr = bm + row;
      float4 v0 = make_float4(0.f,0.f,0.f,0.f), v1 = v0;
      if (gr < M) {
        const float* ap = A + (size_t)gr*DIN + k0 + off;
        v0 = *(const float4*)ap;
        v1 = *(const float4*)(ap + 4);
      }
      short8 pk;
      pk[0]=(short)f2bf(v0.x); pk[1]=(short)f2bf(v0.y); pk[2]=(short)f2bf(v0.z); pk[3]=(short)f2bf(v0.w);
      pk[4]=(short)f2bf(v1.x); pk[5]=(short)f2bf(v1.y); pk[6]=(short)f2bf(v1.z); pk[7]=(short)f2bf(v1.w);
      *(short8*)&As[row*40 + off] = pk;
    }
    // stage W tile 176x32 (bf16 copy from pre-transposed Wt)
    for (int i = t; i < 176*4; i += 256) {
      int c = i >> 2, off = (i & 3) * 8;
      *(uint4*)&Ws[c*40 + off] = *(const uint4*)(Wt + c*DIN + k0 + off);
    }
    __syncthreads();
    short8 a = *(const short8*)&As[(w*16 + r16)*40 + g4*8];
    #pragma unroll
    for (int f = 0; f < 11; ++f) {
      short8 b = *(const short8*)&Ws[(f*16 + r16)*40 + g4*8];
      acc[f] = __builtin_amdgcn_mfma_f32_16x16x32_bf16(a, b, acc[f], 0, 0, 0);
    }
    __syncthreads();
  }
  // epilogue: D row=(lane>>4)*4+r, col=lane&15 (m89-verified)
  #pragma unroll
  for (int f = 0; f < 11; ++f) {
    int c = f*16 + r16;
    #pragma unroll
    for (int r = 0; r < 4; ++r) {
      int row = bm + w*16 + g4*4 + r;
      if (row >= M) continue;
      float v = acc[f][r];
      if (c < HD) hsb[(size_t)row*HD + c] = f2bf(v);
      else if (c < HD+DOUT) loopb[(size_t)row*DOUT + (c-HD)] = f2bf(v);
      else if (c < HD+DOUT+2*NH) scb[(size_t)row*8 + (c-(HD+DOUT))] = v;
    }
  }
}

// ---- CSR build ----
__global__ void hist_k(const int* __restrict__ d1, const int* __restrict__ d2,
                       int* __restrict__ deg) {
  int t = blockIdx.x*blockDim.x + threadIdx.x;
  if (t < EE) atomicAdd(&deg[d1[t]], 1);
  else if (t < 2*EE) atomicAdd(&deg[NN + d2[t-EE]], 1);
}

__global__ __launch_bounds__(256) void scan_sum(const int* __restrict__ deg, int* __restrict__ bsum) {
  int rel = blockIdx.y, b = blockIdx.x, t = threadIdx.x;
  int i = b*256 + t;
  int v = (i < NN) ? deg[rel*NN + i] : 0;
  int lane = t & 63, wv = t >> 6;
  #pragma unroll
  for (int st = 1; st < 64; st <<= 1) v += __shfl_xor(v, st);
  __shared__ int ws[4];
  if (lane == 0) ws[wv] = v;
  __syncthreads();
  if (t == 0) bsum[rel*NCH + b] = ws[0] + ws[1] + ws[2] + ws[3];
}

__global__ __launch_bounds__(256) void scan_mid(int* __restrict__ bsum, int* __restrict__ offs) {
  int rel = blockIdx.x;
  int* bs = bsum + rel*NCH;
  int t = threadIdx.x, lane = t & 63, wv = t >> 6;
  __shared__ int ws[4];
  int v = (t < NCH) ? bs[t] : 0;
  int x = v;
  #pragma unroll
  for (int st = 1; st < 64; st <<= 1) { int y = __shfl_up(x, st); if (lane >= st) x += y; }
  if (lane == 63) ws[wv] = x;
  __syncthreads();
  int add = 0;
  for (int ww = 0; ww < wv; ++ww) add += ws[ww];
  int exc = x - v + add;
  if (t < NCH) bs[t] = exc;
  if (t == 0) offs[rel*(NN+1) + NN] = ws[0] + ws[1] + ws[2] + ws[3];
}

__global__ __launch_bounds__(256) void scan_fin(const int* __restrict__ deg, const int* __restrict__ bsum,
                                                int* __restrict__ offs, int* __restrict__ cursor) {
  int rel = blockIdx.y, b = blockIdx.x, t = threadIdx.x;
  int i = b*256 + t;
  int v = (i < NN) ? deg[rel*NN + i] : 0;
  int lane = t & 63, wv = t >> 6;
  __shared__ int ws[4];
  int x = v;
  #pragma unroll
  for (int st = 1; st < 64; st <<= 1) { int y = __shfl_up(x, st); if (lane >= st) x += y; }
  if (lane == 63) ws[wv] = x;
  __syncthreads();
  int add = bsum[rel*NCH + b];
  for (int ww = 0; ww < wv; ++ww) add += ws[ww];
  int exc = x - v + add;
  if (i < NN) { offs[rel*(NN+1) + i] = exc; cursor[rel*NN + i] = exc; }
}

__global__ void scatter_k(const int* __restrict__ s1, const int* __restrict__ d1,
                          const int* __restrict__ s2, const int* __restrict__ d2,
                          int* __restrict__ cursor,
                          int* __restrict__ sorted1, int* __restrict__ sorted2) {
  int t = blockIdx.x*blockDim.x + threadIdx.x;
  if (t < EE) {
    int pos = atomicAdd(&cursor[d1[t]], 1);
    sorted1[pos] = s1[t];
  } else if (t < 2*EE) {
    int e = t - EE;
    int pos = atomicAdd(&cursor[NN + d2[e]], 1);
    sorted2[pos] = s2[e];
  }
}

// one wave per (dst, 64-col half): single-pass online softmax + gather-sum + fused finalize
__global__ __launch_bounds__(256) void agg_k(const unsigned short* __restrict__ hsb_src,
                                             const unsigned short* __restrict__ loopb_dst,
                                             const float* __restrict__ sc_src,
                                             const float* __restrict__ sc_dst,
                                             const int* __restrict__ offs,
                                             const int* __restrict__ ssrc,
                                             float* __restrict__ out, int N) {
  int gw = (blockIdx.x*blockDim.x + threadIdx.x) >> 6;
  if (gw >= 2*N) return;
  int d = gw >> 1, hf = gw & 1;
  int l = threadIdx.x & 63;
  int hsel = l >> 5;                 // which head of the pair (2hf, 2hf+1)
  float2 er2 = *(const float2*)(sc_dst + (size_t)d*8 + 4 + hf*2);
  float er = hsel ? er2.y : er2.x;
  int beg = offs[d], end = offs[d+1];
  float mx = -1e30f, dn = 0.f, acc = 0.f;
  for (int p = beg; p < end; ++p) {
    int s = __builtin_amdgcn_readfirstlane(ssrc[p]);
    float2 el2 = *(const float2*)(sc_src + (size_t)s*8 + hf*2);
    float el = hsel ? el2.y : el2.x;
    float hv = bf2f(hsb_src[(size_t)s*HD + hf*64 + l]);
    float e = leakyf(el + er);
    if (e > mx) { float cc = __expf(mx - e); acc *= cc; dn *= cc; mx = e; }
    float ex = __expf(e - mx);
    dn += ex;
    acc += ex * hv;
  }
  float v = eluf(acc / fmaxf(dn, 1e-9f));
  v = eluf(v + bf2f(loopb_dst[(size_t)d*DOUT + (l & 31)]));
  out[(size_t)d*HD + hf*64 + l] = v;
}

extern "C" void kernel_launch(void* const* d_in, const int* in_sizes, int n_in,
                              void* d_out, int out_size, void* d_ws, size_t ws_size,
                              hipStream_t stream) {
  const float* feat_user  = (const float*)d_in[0];
  const float* feat_item  = (const float*)d_in[1];
  const int*   src_r1     = (const int*)d_in[2];
  const int*   dst_r1     = (const int*)d_in[3];
  const int*   src_r2     = (const int*)d_in[4];
  const int*   dst_r2     = (const int*)d_in[5];
  const float* fc_r1      = (const float*)d_in[6];
  const float* attn_l_r1  = (const float*)d_in[7];
  const float* attn_r_r1  = (const float*)d_in[8];
  const float* fc_r2      = (const float*)d_in[9];
  const float* attn_l_r2  = (const float*)d_in[10];
  const float* attn_r_r2  = (const float*)d_in[11];
  const float* loopw      = (const float*)d_in[12];

  float* out    = (float*)d_out;
  float* h_user = out;            // from relation 2 (item -> user)
  float* h_item = out + (size_t)NU*HD;  // from relation 1 (user -> item)

  char* ws = (char*)d_ws;
  unsigned short* WtU   = (unsigned short*)ws;            ws += WC*DIN*2;          // 90KB
  unsigned short* WtI   = (unsigned short*)ws;            ws += WC*DIN*2;
  unsigned short* hsbU  = (unsigned short*)ws;            ws += (size_t)NU*HD*2;   // 12.8MB
  unsigned short* hsbI  = (unsigned short*)ws;            ws += (size_t)NI*HD*2;
  unsigned short* loopbU= (unsigned short*)ws;            ws += (size_t)NU*DOUT*2; // 3.2MB
  unsigned short* loopbI= (unsigned short*)ws;            ws += (size_t)NI*DOUT*2;
  float*          scU   = (float*)ws;                     ws += (size_t)NU*8*4;    // 1.6MB
  float*          scI   = (float*)ws;                     ws += (size_t)NI*8*4;
  int*            deg   = (int*)ws;                       ws += 2*NN*4;
  int*            offs  = (int*)ws;                       ws += 2*(NN+1)*4;
  int*            cursor= (int*)ws;                       ws += 2*NN*4;
  int*            bsum  = (int*)ws;                       ws += 2*NCH*4;
  int*            sorted1=(int*)ws;                       ws += (size_t)EE*4;
  int*            sorted2=(int*)ws;                       ws += (size_t)EE*4;

  hipMemsetAsync(deg, 0, sizeof(int)*2*NN, stream);

  // W_user: hs via fc_r1 (user=src of r1), el_r1, er_r2 (user=dst of r2)
  pack_wt<<<(WC*DIN+255)/256, 256, 0, stream>>>(fc_r1, attn_l_r1, fc_r2, attn_r_r2, loopw, WtU);
  // W_item: hs via fc_r2 (item=src of r2), el_r2, er_r1 (item=dst of r1)
  pack_wt<<<(WC*DIN+255)/256, 256, 0, stream>>>(fc_r2, attn_l_r2, fc_r1, attn_r_r1, loopw, WtI);

  hist_k<<<(2*EE + 255)/256, 256, 0, stream>>>(dst_r1, dst_r2, deg);
  scan_sum<<<dim3(NCH,2), 256, 0, stream>>>(deg, bsum);
  scan_mid<<<2, 256, 0, stream>>>(bsum, offs);
  scan_fin<<<dim3(NCH,2), 256, 0, stream>>>(deg, bsum, offs, cursor);
  scatter_k<<<(2*EE + 255)/256, 256, 0, stream>>>(src_r1, dst_r1, src_r2, dst_r2,
                                                  cursor, sorted1, sorted2);

  gemm_mfma<<<(NU+63)/64, 256, 0, stream>>>(feat_user, WtU, hsbU, loopbU, scU, NU);
  gemm_mfma<<<(NI+63)/64, 256, 0, stream>>>(feat_item, WtI, hsbI, loopbI, scI, NI);

  // relation 1: user -> item (dst=item)
  agg_k<<<(NI*2*64 + 255)/256, 256, 0, stream>>>(hsbU, loopbI, scU, scI, offs, sorted1, h_item, NI);
  // relation 2: item -> user (dst=user)
  agg_k<<<(NU*2*64 + 255)/256, 256, 0, stream>>>(hsbI, loopbU, scI, scU, offs + (NN+1), sorted2, h_user, NU);
}

// Round 4
// 471.077 us; speedup vs baseline: 2.4405x; 1.2666x over previous
//
#include <hip/hip_runtime.h>
#include <hip/hip_bf16.h>
#include <cstdint>

#define NU 50000
#define NI 50000
#define NN 50000
#define EE 800000
#define DIN 256
#define NH 4
#define DOUT 32
#define HD 128       // NH*DOUT
#define WC 176       // padded GEMM cols: [hs 128 | loop 32 | el 4 | er 4 | pad 8]
#define NCH 196      // ceil(NN/256)

typedef __attribute__((ext_vector_type(8))) short short8;
typedef __attribute__((ext_vector_type(4))) float f32x4;

__device__ __forceinline__ float leakyf(float x){ return x > 0.f ? x : 0.2f*x; }
__device__ __forceinline__ float eluf(float x){ return x > 0.f ? x : expm1f(x); }
__device__ __forceinline__ unsigned short f2bf(float x){
  unsigned u = __float_as_uint(x);
  return (unsigned short)((u + 0x7FFFu + ((u >> 16) & 1u)) >> 16);   // RNE
}
__device__ __forceinline__ float bf2f(unsigned short b){
  return __uint_as_float(((unsigned)b) << 16);
}
__device__ __forceinline__ unsigned pk2(float x, float y){
  __hip_bfloat162 b = __float22bfloat162_rn(make_float2(x, y));
  union { __hip_bfloat162 b2; unsigned u; } c; c.b2 = b; return c.u;
}

// Wt[c][k] bf16, c<176 (cols 168-175 zero), k<256.
__global__ void pack_wt(const float* __restrict__ fc_a, const float* __restrict__ attn_l_a,
                        const float* __restrict__ fc_b, const float* __restrict__ attn_r_b,
                        const float* __restrict__ loopw, unsigned short* __restrict__ Wt) {
  int t = blockIdx.x*blockDim.x + threadIdx.x;
  if (t >= WC*DIN) return;
  int c = t >> 8, k = t & 255;
  float v = 0.f;
  if (c < HD) v = fc_a[k*HD + c];
  else if (c < HD+DOUT) v = loopw[k*DOUT + (c-HD)];
  else if (c < HD+DOUT+NH) {
    int h = c - (HD+DOUT); float s = 0.f;
    for (int dd = 0; dd < DOUT; ++dd) s += fc_a[k*HD + h*DOUT + dd] * attn_l_a[h*DOUT + dd];
    v = s;
  } else if (c < HD+DOUT+2*NH) {
    int h = c - (HD+DOUT+NH); float s = 0.f;
    for (int dd = 0; dd < DOUT; ++dd) s += fc_b[k*HD + h*DOUT + dd] * attn_r_b[h*DOUT + dd];
    v = s;
  }
  Wt[t] = f2bf(v);
}

// MFMA GEMM: A[M][256] f32 -> (A @ W)[M][176], split-written to hsb/loopb/scb.
__global__ __launch_bounds__(256) void gemm_mfma(const float* __restrict__ A,
                                                 const unsigned short* __restrict__ Wt,
                                                 unsigned short* __restrict__ hsb,
                                                 unsigned short* __restrict__ loopb,
                                                 float* __restrict__ scb, int M) {
  __shared__ __align__(16) unsigned short As[64*40];
  __shared__ __align__(16) unsigned short Ws[176*40];
  int t = threadIdx.x;
  int bm = blockIdx.x * 64;
  int w = t >> 6, l = t & 63;
  int r16 = l & 15, g4 = l >> 4;
  f32x4 acc[11];
  #pragma unroll
  for (int f = 0; f < 11; ++f) acc[f] = (f32x4){0.f,0.f,0.f,0.f};

  for (int k0 = 0; k0 < DIN; k0 += 32) {
    {
      int row = t >> 2, off = (t & 3) * 8;
      int gr = bm + row;
      float4 v0 = make_float4(0.f,0.f,0.f,0.f), v1 = v0;
      if (gr < M) {
        const float* ap = A + (size_t)gr*DIN + k0 + off;
        v0 = *(const float4*)ap;
        v1 = *(const float4*)(ap + 4);
      }
      uint4 pk;
      pk.x = pk2(v0.x, v0.y); pk.y = pk2(v0.z, v0.w);
      pk.z = pk2(v1.x, v1.y); pk.w = pk2(v1.z, v1.w);
      *(uint4*)&As[row*40 + off] = pk;
    }
    for (int i = t; i < 176*4; i += 256) {
      int c = i >> 2, off = (i & 3) * 8;
      *(uint4*)&Ws[c*40 + off] = *(const uint4*)(Wt + c*DIN + k0 + off);
    }
    __syncthreads();
    short8 a = *(const short8*)&As[(w*16 + r16)*40 + g4*8];
    #pragma unroll
    for (int f = 0; f < 11; ++f) {
      short8 b = *(const short8*)&Ws[(f*16 + r16)*40 + g4*8];
      acc[f] = __builtin_amdgcn_mfma_f32_16x16x32_bf16(a, b, acc[f], 0, 0, 0);
    }
    __syncthreads();
  }
  #pragma unroll
  for (int f = 0; f < 11; ++f) {
    int c = f*16 + r16;
    #pragma unroll
    for (int r = 0; r < 4; ++r) {
      int row = bm + w*16 + g4*4 + r;
      if (row >= M) continue;
      float v = acc[f][r];
      if (c < HD) hsb[(size_t)row*HD + c] = f2bf(v);
      else if (c < HD+DOUT) loopb[(size_t)row*DOUT + (c-HD)] = f2bf(v);
      else if (c < HD+DOUT+2*NH) scb[(size_t)row*8 + (c-(HD+DOUT))] = v;
    }
  }
}

// ---- CSR build ----
__global__ void hist_k(const int* __restrict__ d1, const int* __restrict__ d2,
                       int* __restrict__ deg) {
  int t = blockIdx.x*blockDim.x + threadIdx.x;
  if (t < EE) atomicAdd(&deg[d1[t]], 1);
  else if (t < 2*EE) atomicAdd(&deg[NN + d2[t-EE]], 1);
}

__global__ __launch_bounds__(256) void scan_sum(const int* __restrict__ deg, int* __restrict__ bsum) {
  int rel = blockIdx.y, b = blockIdx.x, t = threadIdx.x;
  int i = b*256 + t;
  int v = (i < NN) ? deg[rel*NN + i] : 0;
  int lane = t & 63, wv = t >> 6;
  #pragma unroll
  for (int st = 1; st < 64; st <<= 1) v += __shfl_xor(v, st);
  __shared__ int ws[4];
  if (lane == 0) ws[wv] = v;
  __syncthreads();
  if (t == 0) bsum[rel*NCH + b] = ws[0] + ws[1] + ws[2] + ws[3];
}

__global__ __launch_bounds__(256) void scan_mid(int* __restrict__ bsum, int* __restrict__ offs) {
  int rel = blockIdx.x;
  int* bs = bsum + rel*NCH;
  int t = threadIdx.x, lane = t & 63, wv = t >> 6;
  __shared__ int ws[4];
  int v = (t < NCH) ? bs[t] : 0;
  int x = v;
  #pragma unroll
  for (int st = 1; st < 64; st <<= 1) { int y = __shfl_up(x, st); if (lane >= st) x += y; }
  if (lane == 63) ws[wv] = x;
  __syncthreads();
  int add = 0;
  for (int ww = 0; ww < wv; ++ww) add += ws[ww];
  int exc = x - v + add;
  if (t < NCH) bs[t] = exc;
  if (t == 0) offs[rel*(NN+1) + NN] = ws[0] + ws[1] + ws[2] + ws[3];
}

__global__ __launch_bounds__(256) void scan_fin(const int* __restrict__ deg, const int* __restrict__ bsum,
                                                int* __restrict__ offs, int* __restrict__ cursor) {
  int rel = blockIdx.y, b = blockIdx.x, t = threadIdx.x;
  int i = b*256 + t;
  int v = (i < NN) ? deg[rel*NN + i] : 0;
  int lane = t & 63, wv = t >> 6;
  __shared__ int ws[4];
  int x = v;
  #pragma unroll
  for (int st = 1; st < 64; st <<= 1) { int y = __shfl_up(x, st); if (lane >= st) x += y; }
  if (lane == 63) ws[wv] = x;
  __syncthreads();
  int add = bsum[rel*NCH + b];
  for (int ww = 0; ww < wv; ++ww) add += ws[ww];
  int exc = x - v + add;
  if (i < NN) { offs[rel*(NN+1) + i] = exc; cursor[rel*NN + i] = exc; }
}

__global__ void scatter_k(const int* __restrict__ s1, const int* __restrict__ d1,
                          const int* __restrict__ s2, const int* __restrict__ d2,
                          int* __restrict__ cursor,
                          int* __restrict__ sorted1, int* __restrict__ sorted2) {
  int t = blockIdx.x*blockDim.x + threadIdx.x;
  if (t < EE) {
    int pos = atomicAdd(&cursor[d1[t]], 1);
    sorted1[pos] = s1[t];
  } else if (t < 2*EE) {
    int e = t - EE;
    int pos = atomicAdd(&cursor[NN + d2[e]], 1);
    sorted2[pos] = s2[e];
  }
}

// one wave per (rel, dst): edge-parallel segment softmax -> normalized weights.
// lane layout: h = l>>4 (4 heads), q = l&15 (16 edges/chunk).
__global__ __launch_bounds__(256) void weight_k(const float* __restrict__ scU,
                                                const float* __restrict__ scI,
                                                const int* __restrict__ offs,
                                                const int* __restrict__ sorted1,
                                                const int* __restrict__ sorted2,
                                                float* __restrict__ w1,
                                                float* __restrict__ w2) {
  int gw = (blockIdx.x*blockDim.x + threadIdx.x) >> 6;
  if (gw >= 2*NN) return;
  int rel = gw >= NN;
  int d = rel ? gw - NN : gw;
  const float* sc_src = rel ? scI : scU;
  const float* sc_dst = rel ? scU : scI;
  const int*   of = offs + rel*(NN+1);
  const int*   ss = rel ? sorted2 : sorted1;
  float*       wb = rel ? w2 : w1;
  int beg = of[d], end = of[d+1];
  if (beg >= end) return;
  int l = threadIdx.x & 63, h = l >> 4, q = l & 15;
  float er = sc_dst[(size_t)d*8 + 4 + h];
  float e_cache[4];
  // pass 1: scores + segment max (16-lane tree per head group)
  float mx = -1e30f;
  int nch = 0;
  for (int p0 = beg; p0 < end; p0 += 16, ++nch) {
    int p = p0 + q;
    float e = -1e30f;
    if (p < end) {
      int s = ss[p];
      e = leakyf(sc_src[(size_t)s*8 + h] + er);
    }
    if (nch < 4) e_cache[nch] = e;
    mx = fmaxf(mx, e);
  }
  #pragma unroll
  for (int st = 1; st < 16; st <<= 1) mx = fmaxf(mx, __shfl_xor(mx, st));
  // pass 2: ex (cached chunks stay in regs), accumulate denom
  float dnp = 0.f;
  int c = 0;
  for (int p0 = beg; p0 < end; p0 += 16, ++c) {
    int p = p0 + q;
    float e;
    if (c < 4) e = e_cache[c];
    else {
      e = -1e30f;
      if (p < end) { int s = ss[p]; e = leakyf(sc_src[(size_t)s*8 + h] + er); }
    }
    float ex = (p < end) ? __expf(e - mx) : 0.f;
    if (c < 4) e_cache[c] = ex;
    dnp += ex;
  }
  #pragma unroll
  for (int st = 1; st < 16; st <<= 1) dnp += __shfl_xor(dnp, st);
  float rdn = 1.f / dnp;
  // pass 3: write normalized weights
  c = 0;
  for (int p0 = beg; p0 < end; p0 += 16, ++c) {
    int p = p0 + q;
    if (p < end) {
      float ex;
      if (c < 4) ex = e_cache[c];
      else { int s = ss[p]; ex = __expf(leakyf(sc_src[(size_t)s*8 + h] + er) - mx); }
      wb[(size_t)p*4 + h] = ex * rdn;
    }
  }
}

// one wave per (rel, dst, 64-col half): pure weighted gather-sum + fused finalize
__global__ __launch_bounds__(256) void agg_k(const unsigned short* __restrict__ hsbU,
                                             const unsigned short* __restrict__ hsbI,
                                             const unsigned short* __restrict__ loopbU,
                                             const unsigned short* __restrict__ loopbI,
                                             const float* __restrict__ w1,
                                             const float* __restrict__ w2,
                                             const int* __restrict__ offs,
                                             const int* __restrict__ sorted1,
                                             const int* __restrict__ sorted2,
                                             float* __restrict__ out) {
  int gw = (blockIdx.x*blockDim.x + threadIdx.x) >> 6;
  if (gw >= 4*NN) return;
  int rel = gw >= 2*NN;               // 0: r1 -> h_item; 1: r2 -> h_user
  int gg = rel ? gw - 2*NN : gw;
  int d = gg >> 1, hf = gg & 1;
  const unsigned short* hsb = rel ? hsbI : hsbU;     // src features
  const unsigned short* lpb = rel ? loopbU : loopbI; // dst loop proj
  const float* wb = rel ? w2 : w1;
  const int*   of = offs + rel*(NN+1);
  const int*   ss = rel ? sorted2 : sorted1;
  float* o = rel ? out : out + (size_t)NN*HD;        // h_user first, h_item second
  int l = threadIdx.x & 63;
  int myh = hf*2 + (l >> 5);
  int beg = of[d], end = of[d+1];
  float acc0 = 0.f, acc1 = 0.f;
  int p = beg;
  for (; p + 2 <= end; p += 2) {
    int s0 = __builtin_amdgcn_readfirstlane(ss[p]);
    int s1 = __builtin_amdgcn_readfirstlane(ss[p+1]);
    float w0 = wb[(size_t)p*4 + myh];
    float w1v = wb[(size_t)(p+1)*4 + myh];
    float h0 = bf2f(hsb[(size_t)s0*HD + hf*64 + l]);
    float h1 = bf2f(hsb[(size_t)s1*HD + hf*64 + l]);
    acc0 += w0*h0; acc1 += w1v*h1;
  }
  if (p < end) {
    int s0 = __builtin_amdgcn_readfirstlane(ss[p]);
    float w0 = wb[(size_t)p*4 + myh];
    acc0 += w0 * bf2f(hsb[(size_t)s0*HD + hf*64 + l]);
  }
  float v = eluf(acc0 + acc1);
  v = eluf(v + bf2f(lpb[(size_t)d*DOUT + (l & 31)]));
  o[(size_t)d*HD + hf*64 + l] = v;
}

extern "C" void kernel_launch(void* const* d_in, const int* in_sizes, int n_in,
                              void* d_out, int out_size, void* d_ws, size_t ws_size,
                              hipStream_t stream) {
  const float* feat_user  = (const float*)d_in[0];
  const float* feat_item  = (const float*)d_in[1];
  const int*   src_r1     = (const int*)d_in[2];
  const int*   dst_r1     = (const int*)d_in[3];
  const int*   src_r2     = (const int*)d_in[4];
  const int*   dst_r2     = (const int*)d_in[5];
  const float* fc_r1      = (const float*)d_in[6];
  const float* attn_l_r1  = (const float*)d_in[7];
  const float* attn_r_r1  = (const float*)d_in[8];
  const float* fc_r2      = (const float*)d_in[9];
  const float* attn_l_r2  = (const float*)d_in[10];
  const float* attn_r_r2  = (const float*)d_in[11];
  const float* loopw      = (const float*)d_in[12];

  float* out = (float*)d_out;

  char* ws = (char*)d_ws;
  unsigned short* WtU   = (unsigned short*)ws;            ws += WC*DIN*2;
  unsigned short* WtI   = (unsigned short*)ws;            ws += WC*DIN*2;
  unsigned short* hsbU  = (unsigned short*)ws;            ws += (size_t)NU*HD*2;
  unsigned short* hsbI  = (unsigned short*)ws;            ws += (size_t)NI*HD*2;
  unsigned short* loopbU= (unsigned short*)ws;            ws += (size_t)NU*DOUT*2;
  unsigned short* loopbI= (unsigned short*)ws;            ws += (size_t)NI*DOUT*2;
  float*          scU   = (float*)ws;                     ws += (size_t)NU*8*4;
  float*          scI   = (float*)ws;                     ws += (size_t)NI*8*4;
  int*            deg   = (int*)ws;                       ws += 2*NN*4;
  int*            offs  = (int*)ws;                       ws += 2*(NN+1)*4;
  int*            cursor= (int*)ws;                       ws += 2*NN*4;
  int*            bsum  = (int*)ws;                       ws += 2*NCH*4;
  int*            sorted1=(int*)ws;                       ws += (size_t)EE*4;
  int*            sorted2=(int*)ws;                       ws += (size_t)EE*4;
  float*          w1    = (float*)ws;                     ws += (size_t)EE*NH*4;
  float*          w2    = (float*)ws;                     ws += (size_t)EE*NH*4;

  hipMemsetAsync(deg, 0, sizeof(int)*2*NN, stream);

  pack_wt<<<(WC*DIN+255)/256, 256, 0, stream>>>(fc_r1, attn_l_r1, fc_r2, attn_r_r2, loopw, WtU);
  pack_wt<<<(WC*DIN+255)/256, 256, 0, stream>>>(fc_r2, attn_l_r2, fc_r1, attn_r_r1, loopw, WtI);

  hist_k<<<(2*EE + 255)/256, 256, 0, stream>>>(dst_r1, dst_r2, deg);
  scan_sum<<<dim3(NCH,2), 256, 0, stream>>>(deg, bsum);
  scan_mid<<<2, 256, 0, stream>>>(bsum, offs);
  scan_fin<<<dim3(NCH,2), 256, 0, stream>>>(deg, bsum, offs, cursor);
  scatter_k<<<(2*EE + 255)/256, 256, 0, stream>>>(src_r1, dst_r1, src_r2, dst_r2,
                                                  cursor, sorted1, sorted2);

  gemm_mfma<<<(NU+63)/64, 256, 0, stream>>>(feat_user, WtU, hsbU, loopbU, scU, NU);
  gemm_mfma<<<(NI+63)/64, 256, 0, stream>>>(feat_item, WtI, hsbI, loopbI, scI, NI);

  weight_k<<<(2*NN*64 + 255)/256, 256, 0, stream>>>(scU, scI, offs, sorted1, sorted2, w1, w2);
  agg_k<<<(4*NN*64 + 255)/256, 256, 0, stream>>>(hsbU, hsbI, loopbU, loopbI, w1, w2,
                                                 offs, sorted1, sorted2, out);
}

// Round 5
// 346.618 us; speedup vs baseline: 3.3168x; 1.3591x over previous
//
#include <hip/hip_runtime.h>
#include <hip/hip_bf16.h>
#include <cstdint>

#define NU 50000
#define NI 50000
#define NN 50000
#define EE 800000
#define DIN 256
#define NH 4
#define DOUT 32
#define HD 128       // NH*DOUT
#define WC 176       // padded GEMM cols: [hs 128 | loop 32 | el 4 | er 4 | pad 8]
#define NCH 196      // ceil(NN/256)

typedef __attribute__((ext_vector_type(8))) short short8;
typedef __attribute__((ext_vector_type(4))) float f32x4;

__device__ __forceinline__ float leakyf(float x){ return x > 0.f ? x : 0.2f*x; }
__device__ __forceinline__ float eluf(float x){ return x > 0.f ? x : expm1f(x); }
__device__ __forceinline__ unsigned short f2bf(float x){
  unsigned u = __float_as_uint(x);
  return (unsigned short)((u + 0x7FFFu + ((u >> 16) & 1u)) >> 16);   // RNE
}
__device__ __forceinline__ float bf2f(unsigned short b){
  return __uint_as_float(((unsigned)b) << 16);
}
__device__ __forceinline__ float bflo(unsigned r){ return __uint_as_float(r << 16); }
__device__ __forceinline__ float bfhi(unsigned r){ return __uint_as_float(r & 0xffff0000u); }
__device__ __forceinline__ unsigned pk2(float x, float y){
  __hip_bfloat162 b = __float22bfloat162_rn(make_float2(x, y));
  union { __hip_bfloat162 b2; unsigned u; } c; c.b2 = b; return c.u;
}

// Wt[c][k] bf16, c<176 (cols 168-175 zero), k<256.
__global__ void pack_wt(const float* __restrict__ fc_a, const float* __restrict__ attn_l_a,
                        const float* __restrict__ fc_b, const float* __restrict__ attn_r_b,
                        const float* __restrict__ loopw, unsigned short* __restrict__ Wt) {
  int t = blockIdx.x*blockDim.x + threadIdx.x;
  if (t >= WC*DIN) return;
  int c = t >> 8, k = t & 255;
  float v = 0.f;
  if (c < HD) v = fc_a[k*HD + c];
  else if (c < HD+DOUT) v = loopw[k*DOUT + (c-HD)];
  else if (c < HD+DOUT+NH) {
    int h = c - (HD+DOUT); float s = 0.f;
    for (int dd = 0; dd < DOUT; ++dd) s += fc_a[k*HD + h*DOUT + dd] * attn_l_a[h*DOUT + dd];
    v = s;
  } else if (c < HD+DOUT+2*NH) {
    int h = c - (HD+DOUT+NH); float s = 0.f;
    for (int dd = 0; dd < DOUT; ++dd) s += fc_b[k*HD + h*DOUT + dd] * attn_r_b[h*DOUT + dd];
    v = s;
  }
  Wt[t] = f2bf(v);
}

// MFMA GEMM: A[M][256] f32 -> (A @ W)[M][176], split-written to hsb/loopb/scb.
// 512 thr = 8 waves, tile 128 rows. Wave w: rows w*16..w*16+15, all 11 col-frags.
__global__ __launch_bounds__(512) void gemm_mfma(const float* __restrict__ A,
                                                 const unsigned short* __restrict__ Wt,
                                                 unsigned short* __restrict__ hsb,
                                                 unsigned short* __restrict__ loopb,
                                                 float* __restrict__ scb, int M) {
  __shared__ __align__(16) unsigned short As[128*40];
  __shared__ __align__(16) unsigned short Ws[176*40];
  int t = threadIdx.x;
  int bm = blockIdx.x * 128;
  int w = t >> 6, l = t & 63;
  int r16 = l & 15, g4 = l >> 4;
  f32x4 acc[11];
  #pragma unroll
  for (int f = 0; f < 11; ++f) acc[f] = (f32x4){0.f,0.f,0.f,0.f};

  for (int k0 = 0; k0 < DIN; k0 += 32) {
    {
      int row = t >> 2, off = (t & 3) * 8;
      int gr = bm + row;
      float4 v0 = make_float4(0.f,0.f,0.f,0.f), v1 = v0;
      if (gr < M) {
        const float* ap = A + (size_t)gr*DIN + k0 + off;
        v0 = *(const float4*)ap;
        v1 = *(const float4*)(ap + 4);
      }
      uint4 pk;
      pk.x = pk2(v0.x, v0.y); pk.y = pk2(v0.z, v0.w);
      pk.z = pk2(v1.x, v1.y); pk.w = pk2(v1.z, v1.w);
      *(uint4*)&As[row*40 + off] = pk;
    }
    for (int i = t; i < 176*4; i += 512) {
      int c = i >> 2, off = (i & 3) * 8;
      *(uint4*)&Ws[c*40 + off] = *(const uint4*)(Wt + c*DIN + k0 + off);
    }
    __syncthreads();
    short8 a = *(const short8*)&As[(w*16 + r16)*40 + g4*8];
    #pragma unroll
    for (int f = 0; f < 11; ++f) {
      short8 b = *(const short8*)&Ws[(f*16 + r16)*40 + g4*8];
      acc[f] = __builtin_amdgcn_mfma_f32_16x16x32_bf16(a, b, acc[f], 0, 0, 0);
    }
    __syncthreads();
  }
  #pragma unroll
  for (int f = 0; f < 11; ++f) {
    int c = f*16 + r16;
    #pragma unroll
    for (int r = 0; r < 4; ++r) {
      int row = bm + w*16 + g4*4 + r;
      if (row >= M) continue;
      float v = acc[f][r];
      if (c < HD) hsb[(size_t)row*HD + c] = f2bf(v);
      else if (c < HD+DOUT) loopb[(size_t)row*DOUT + (c-HD)] = f2bf(v);
      else if (c < HD+DOUT+2*NH) scb[(size_t)row*8 + (c-(HD+DOUT))] = v;
    }
  }
}

// ---- CSR build ----
__global__ void hist_k(const int* __restrict__ d1, const int* __restrict__ d2,
                       int* __restrict__ deg) {
  int t = blockIdx.x*blockDim.x + threadIdx.x;
  if (t < EE) atomicAdd(&deg[d1[t]], 1);
  else if (t < 2*EE) atomicAdd(&deg[NN + d2[t-EE]], 1);
}

__global__ __launch_bounds__(256) void scan_sum(const int* __restrict__ deg, int* __restrict__ bsum) {
  int rel = blockIdx.y, b = blockIdx.x, t = threadIdx.x;
  int i = b*256 + t;
  int v = (i < NN) ? deg[rel*NN + i] : 0;
  int lane = t & 63, wv = t >> 6;
  #pragma unroll
  for (int st = 1; st < 64; st <<= 1) v += __shfl_xor(v, st);
  __shared__ int ws[4];
  if (lane == 0) ws[wv] = v;
  __syncthreads();
  if (t == 0) bsum[rel*NCH + b] = ws[0] + ws[1] + ws[2] + ws[3];
}

__global__ __launch_bounds__(256) void scan_mid(int* __restrict__ bsum, int* __restrict__ offs) {
  int rel = blockIdx.x;
  int* bs = bsum + rel*NCH;
  int t = threadIdx.x, lane = t & 63, wv = t >> 6;
  __shared__ int ws[4];
  int v = (t < NCH) ? bs[t] : 0;
  int x = v;
  #pragma unroll
  for (int st = 1; st < 64; st <<= 1) { int y = __shfl_up(x, st); if (lane >= st) x += y; }
  if (lane == 63) ws[wv] = x;
  __syncthreads();
  int add = 0;
  for (int ww = 0; ww < wv; ++ww) add += ws[ww];
  int exc = x - v + add;
  if (t < NCH) bs[t] = exc;
  if (t == 0) offs[rel*(NN+1) + NN] = ws[0] + ws[1] + ws[2] + ws[3];
}

__global__ __launch_bounds__(256) void scan_fin(const int* __restrict__ deg, const int* __restrict__ bsum,
                                                int* __restrict__ offs, int* __restrict__ cursor) {
  int rel = blockIdx.y, b = blockIdx.x, t = threadIdx.x;
  int i = b*256 + t;
  int v = (i < NN) ? deg[rel*NN + i] : 0;
  int lane = t & 63, wv = t >> 6;
  __shared__ int ws[4];
  int x = v;
  #pragma unroll
  for (int st = 1; st < 64; st <<= 1) { int y = __shfl_up(x, st); if (lane >= st) x += y; }
  if (lane == 63) ws[wv] = x;
  __syncthreads();
  int add = bsum[rel*NCH + b];
  for (int ww = 0; ww < wv; ++ww) add += ws[ww];
  int exc = x - v + add;
  if (i < NN) { offs[rel*(NN+1) + i] = exc; cursor[rel*NN + i] = exc; }
}

__global__ void scatter_k(const int* __restrict__ s1, const int* __restrict__ d1,
                          const int* __restrict__ s2, const int* __restrict__ d2,
                          int* __restrict__ cursor,
                          int* __restrict__ sorted1, int* __restrict__ sorted2) {
  int t = blockIdx.x*blockDim.x + threadIdx.x;
  if (t < EE) {
    int pos = atomicAdd(&cursor[d1[t]], 1);
    sorted1[pos] = s1[t];
  } else if (t < 2*EE) {
    int e = t - EE;
    int pos = atomicAdd(&cursor[NN + d2[e]], 1);
    sorted2[pos] = s2[e];
  }
}

// one wave per (rel, dst): edge-parallel segment softmax -> normalized weights.
// lane layout: h = l>>4 (4 heads), q = l&15 (16 edges/chunk).
__global__ __launch_bounds__(256) void weight_k(const float* __restrict__ scU,
                                                const float* __restrict__ scI,
                                                const int* __restrict__ offs,
                                                const int* __restrict__ sorted1,
                                                const int* __restrict__ sorted2,
                                                float* __restrict__ w1,
                                                float* __restrict__ w2) {
  int gw = (blockIdx.x*blockDim.x + threadIdx.x) >> 6;
  if (gw >= 2*NN) return;
  int rel = gw >= NN;
  int d = rel ? gw - NN : gw;
  const float* sc_src = rel ? scI : scU;
  const float* sc_dst = rel ? scU : scI;
  const int*   of = offs + rel*(NN+1);
  const int*   ss = rel ? sorted2 : sorted1;
  float*       wb = rel ? w2 : w1;
  int beg = of[d], end = of[d+1];
  if (beg >= end) return;
  int l = threadIdx.x & 63, h = l >> 4, q = l & 15;
  float er = sc_dst[(size_t)d*8 + 4 + h];
  float e_cache[4];
  float mx = -1e30f;
  int nch = 0;
  for (int p0 = beg; p0 < end; p0 += 16, ++nch) {
    int p = p0 + q;
    float e = -1e30f;
    if (p < end) {
      int s = ss[p];
      e = leakyf(sc_src[(size_t)s*8 + h] + er);
    }
    if (nch < 4) e_cache[nch] = e;
    mx = fmaxf(mx, e);
  }
  #pragma unroll
  for (int st = 1; st < 16; st <<= 1) mx = fmaxf(mx, __shfl_xor(mx, st));
  float dnp = 0.f;
  int c = 0;
  for (int p0 = beg; p0 < end; p0 += 16, ++c) {
    int p = p0 + q;
    float e;
    if (c < 4) e = e_cache[c];
    else {
      e = -1e30f;
      if (p < end) { int s = ss[p]; e = leakyf(sc_src[(size_t)s*8 + h] + er); }
    }
    float ex = (p < end) ? __expf(e - mx) : 0.f;
    if (c < 4) e_cache[c] = ex;
    dnp += ex;
  }
  #pragma unroll
  for (int st = 1; st < 16; st <<= 1) dnp += __shfl_xor(dnp, st);
  float rdn = 1.f / dnp;
  c = 0;
  for (int p0 = beg; p0 < end; p0 += 16, ++c) {
    int p = p0 + q;
    if (p < end) {
      float ex;
      if (c < 4) ex = e_cache[c];
      else { int s = ss[p]; ex = __expf(leakyf(sc_src[(size_t)s*8 + h] + er) - mx); }
      wb[(size_t)p*4 + h] = ex * rdn;
    }
  }
}

// one wave per (rel, dst): lane l covers cols 2l, 2l+1 (uint load = full 256B row/edge).
__global__ __launch_bounds__(256) void agg_k(const unsigned short* __restrict__ hsbU,
                                             const unsigned short* __restrict__ hsbI,
                                             const unsigned short* __restrict__ loopbU,
                                             const unsigned short* __restrict__ loopbI,
                                             const float* __restrict__ w1,
                                             const float* __restrict__ w2,
                                             const int* __restrict__ offs,
                                             const int* __restrict__ sorted1,
                                             const int* __restrict__ sorted2,
                                             float* __restrict__ out) {
  int gw = __builtin_amdgcn_readfirstlane((blockIdx.x*blockDim.x + threadIdx.x) >> 6);
  if (gw >= 2*NN) return;
  int rel = gw >= NN;
  int d = rel ? gw - NN : gw;
  const unsigned short* hsb = rel ? hsbI : hsbU;     // src features
  const unsigned short* lpb = rel ? loopbU : loopbI; // dst loop proj
  const float* wb = rel ? w2 : w1;
  const int*   of = offs + rel*(NN+1);
  const int*   ss = rel ? sorted2 : sorted1;
  float* o = (rel ? out : out + (size_t)NN*HD) + (size_t)d*HD;
  int l = threadIdx.x & 63;
  int h = l >> 4;                       // head of cols 2l, 2l+1
  int beg = of[d], end = of[d+1];
  float aL0=0.f,aH0=0.f,aL1=0.f,aH1=0.f,aL2=0.f,aH2=0.f,aL3=0.f,aH3=0.f;
  int p = beg;
  for (; p + 4 <= end; p += 4) {
    int s0 = __builtin_amdgcn_readfirstlane(ss[p]);
    int s1 = __builtin_amdgcn_readfirstlane(ss[p+1]);
    int s2 = __builtin_amdgcn_readfirstlane(ss[p+2]);
    int s3 = __builtin_amdgcn_readfirstlane(ss[p+3]);
    float w0 = wb[(size_t)p*4 + h];
    float w1v = wb[(size_t)(p+1)*4 + h];
    float w2v = wb[(size_t)(p+2)*4 + h];
    float w3v = wb[(size_t)(p+3)*4 + h];
    unsigned r0 = *(const unsigned*)&hsb[(size_t)s0*HD + 2*l];
    unsigned r1 = *(const unsigned*)&hsb[(size_t)s1*HD + 2*l];
    unsigned r2 = *(const unsigned*)&hsb[(size_t)s2*HD + 2*l];
    unsigned r3 = *(const unsigned*)&hsb[(size_t)s3*HD + 2*l];
    aL0 = fmaf(w0,  bflo(r0), aL0); aH0 = fmaf(w0,  bfhi(r0), aH0);
    aL1 = fmaf(w1v, bflo(r1), aL1); aH1 = fmaf(w1v, bfhi(r1), aH1);
    aL2 = fmaf(w2v, bflo(r2), aL2); aH2 = fmaf(w2v, bfhi(r2), aH2);
    aL3 = fmaf(w3v, bflo(r3), aL3); aH3 = fmaf(w3v, bfhi(r3), aH3);
  }
  for (; p < end; ++p) {
    int s0 = __builtin_amdgcn_readfirstlane(ss[p]);
    float w0 = wb[(size_t)p*4 + h];
    unsigned r0 = *(const unsigned*)&hsb[(size_t)s0*HD + 2*l];
    aL0 = fmaf(w0, bflo(r0), aL0); aH0 = fmaf(w0, bfhi(r0), aH0);
  }
  float vL = eluf((aL0+aL1)+(aL2+aL3));
  float vH = eluf((aH0+aH1)+(aH2+aH3));
  unsigned lp2 = *(const unsigned*)&lpb[(size_t)d*DOUT + ((2*l) & 31)];
  vL = eluf(vL + bflo(lp2));
  vH = eluf(vH + bfhi(lp2));
  *(float2*)&o[2*l] = make_float2(vL, vH);
}

extern "C" void kernel_launch(void* const* d_in, const int* in_sizes, int n_in,
                              void* d_out, int out_size, void* d_ws, size_t ws_size,
                              hipStream_t stream) {
  const float* feat_user  = (const float*)d_in[0];
  const float* feat_item  = (const float*)d_in[1];
  const int*   src_r1     = (const int*)d_in[2];
  const int*   dst_r1     = (const int*)d_in[3];
  const int*   src_r2     = (const int*)d_in[4];
  const int*   dst_r2     = (const int*)d_in[5];
  const float* fc_r1      = (const float*)d_in[6];
  const float* attn_l_r1  = (const float*)d_in[7];
  const float* attn_r_r1  = (const float*)d_in[8];
  const float* fc_r2      = (const float*)d_in[9];
  const float* attn_l_r2  = (const float*)d_in[10];
  const float* attn_r_r2  = (const float*)d_in[11];
  const float* loopw      = (const float*)d_in[12];

  float* out = (float*)d_out;

  char* ws = (char*)d_ws;
  unsigned short* WtU   = (unsigned short*)ws;            ws += WC*DIN*2;
  unsigned short* WtI   = (unsigned short*)ws;            ws += WC*DIN*2;
  unsigned short* hsbU  = (unsigned short*)ws;            ws += (size_t)NU*HD*2;
  unsigned short* hsbI  = (unsigned short*)ws;            ws += (size_t)NI*HD*2;
  unsigned short* loopbU= (unsigned short*)ws;            ws += (size_t)NU*DOUT*2;
  unsigned short* loopbI= (unsigned short*)ws;            ws += (size_t)NI*DOUT*2;
  float*          scU   = (float*)ws;                     ws += (size_t)NU*8*4;
  float*          scI   = (float*)ws;                     ws += (size_t)NI*8*4;
  int*            deg   = (int*)ws;                       ws += 2*NN*4;
  int*            offs  = (int*)ws;                       ws += 2*(NN+1)*4;
  int*            cursor= (int*)ws;                       ws += 2*NN*4;
  int*            bsum  = (int*)ws;                       ws += 2*NCH*4;
  int*            sorted1=(int*)ws;                       ws += (size_t)EE*4;
  int*            sorted2=(int*)ws;                       ws += (size_t)EE*4;
  float*          w1    = (float*)ws;                     ws += (size_t)EE*NH*4;
  float*          w2    = (float*)ws;                     ws += (size_t)EE*NH*4;

  hipMemsetAsync(deg, 0, sizeof(int)*2*NN, stream);

  pack_wt<<<(WC*DIN+255)/256, 256, 0, stream>>>(fc_r1, attn_l_r1, fc_r2, attn_r_r2, loopw, WtU);
  pack_wt<<<(WC*DIN+255)/256, 256, 0, stream>>>(fc_r2, attn_l_r2, fc_r1, attn_r_r1, loopw, WtI);

  hist_k<<<(2*EE + 255)/256, 256, 0, stream>>>(dst_r1, dst_r2, deg);
  scan_sum<<<dim3(NCH,2), 256, 0, stream>>>(deg, bsum);
  scan_mid<<<2, 256, 0, stream>>>(bsum, offs);
  scan_fin<<<dim3(NCH,2), 256, 0, stream>>>(deg, bsum, offs, cursor);
  scatter_k<<<(2*EE + 255)/256, 256, 0, stream>>>(src_r1, dst_r1, src_r2, dst_r2,
                                                  cursor, sorted1, sorted2);

  gemm_mfma<<<(NU+127)/128, 512, 0, stream>>>(feat_user, WtU, hsbU, loopbU, scU, NU);
  gemm_mfma<<<(NI+127)/128, 512, 0, stream>>>(feat_item, WtI, hsbI, loopbI, scI, NI);

  weight_k<<<(2*NN*64 + 255)/256, 256, 0, stream>>>(scU, scI, offs, sorted1, sorted2, w1, w2);
  agg_k<<<(2*NN*64 + 255)/256, 256, 0, stream>>>(hsbU, hsbI, loopbU, loopbI, w1, w2,
                                                 offs, sorted1, sorted2, out);
}